// Round 6
// baseline (331.797 us; speedup 1.0000x reference)
//
#include <hip/hip_runtime.h>
#include <hip/hip_bf16.h>

#define NN 100000
#define NE 1600000
#define HID 64
#define ALPHA 0.1f
#define COEF 0.3f   // (1-ALPHA)/K

#define NBK 196            // buckets of 512 nodes: dst>>9
#define SBLK 256           // blocks for hist/scatter passes
#define EB_PER_BLK (NE / SBLK)   // 6250
#define HTOT (NBK * SBLK)        // 50176 = 49 * 1024

__device__ __forceinline__ float bf2f(unsigned short u) {
    union { unsigned int i; float f; } v; v.i = ((unsigned int)u) << 16; return v.f;
}
__device__ __forceinline__ unsigned short f2bf(float f) {
    union { float f; unsigned int i; } v; v.f = f;
    unsigned int r = v.i + 0x7FFF + ((v.i >> 16) & 1);
    return (unsigned short)(r >> 16);
}
// lo gets exact bf16; hi keeps low-16-bit mantissa contamination (<=1 ulp bf16) — saves the AND
__device__ __forceinline__ void acc2(float& lo, float& hi, unsigned int u) {
    union { unsigned int i; float f; } a, b;
    a.i = u << 16; b.i = u;
    lo += a.f; hi += b.f;
}
__device__ __forceinline__ void up2(float& lo, float& hi, unsigned int u) {
    union { unsigned int i; float f; } a, b;
    a.i = u << 16; b.i = u & 0xFFFF0000u;
    lo = a.f; hi = b.f;
}
__device__ __forceinline__ unsigned int pk2(float lo, float hi) {
    return (unsigned int)f2bf(lo) | ((unsigned int)f2bf(hi) << 16);
}

// ---------------- bucketed CSR build (no global atomics) ----------------

__global__ void histA_kernel(const int* __restrict__ dst, int* __restrict__ hist) {
    __shared__ int cnt[NBK];
    const int b = blockIdx.x, t = threadIdx.x;
    for (int i = t; i < NBK; i += 256) cnt[i] = 0;
    __syncthreads();
    const int beg = b * EB_PER_BLK, end = beg + EB_PER_BLK;
    for (int e = beg + t; e < end; e += 256)
        atomicAdd(&cnt[dst[e] >> 9], 1);
    __syncthreads();
    for (int i = t; i < NBK; i += 256)
        hist[i * SBLK + b] = cnt[i];
}

// coalesced 2-kernel scan of hist[HTOT]
__global__ void scanHA_kernel(const int* __restrict__ hist, int* __restrict__ hsum) {
    __shared__ int red[16];
    const int b = blockIdx.x, t = threadIdx.x;
    int v = hist[b * 1024 + t];
    for (int o = 32; o > 0; o >>= 1) v += __shfl_down(v, o, 64);
    if ((t & 63) == 0) red[t >> 6] = v;
    __syncthreads();
    if (t < 64) {
        int s = (t < 16) ? red[t] : 0;
        for (int o = 8; o > 0; o >>= 1) s += __shfl_down(s, o, 64);
        if (t == 0) hsum[b] = s;
    }
}

__global__ void scanHC_kernel(int* __restrict__ hist, const int* __restrict__ hsum) {
    __shared__ int ts[1024];
    __shared__ int s_off;
    const int b = blockIdx.x, t = threadIdx.x;
    int v = hist[b * 1024 + t];
    ts[t] = v;
    if (t == 0) {
        int o = 0;
        for (int i = 0; i < b; ++i) o += hsum[i];
        s_off = o;
    }
    __syncthreads();
    for (int off = 1; off < 1024; off <<= 1) {
        int w = (t >= off) ? ts[t - off] : 0;
        __syncthreads();
        if (t >= off) ts[t] += w;
        __syncthreads();
    }
    hist[b * 1024 + t] = s_off + ((t > 0) ? ts[t - 1] : 0);
}

__global__ void scatterB_kernel(const int* __restrict__ src, const int* __restrict__ dst,
                                const int* __restrict__ hist, unsigned int* __restrict__ buck) {
    __shared__ int cur[NBK];
    const int b = blockIdx.x, t = threadIdx.x;
    for (int i = t; i < NBK; i += 256) cur[i] = hist[i * SBLK + b];
    __syncthreads();
    const int beg = b * EB_PER_BLK, end = beg + EB_PER_BLK;
    for (int e = beg + t; e < end; e += 256) {
        int d = dst[e];
        int pos = atomicAdd(&cur[d >> 9], 1);
        buck[pos] = ((unsigned int)src[e] << 9) | (unsigned int)(d & 511);
    }
}

// Per-bucket: rowptr/dinv/rdinv + csr scatter + fused g0 (gA = bf16(dinv*x))
__global__ void bucketC_kernel(const unsigned int* __restrict__ buck, const int* __restrict__ hist,
                               int* __restrict__ rowptr, float* __restrict__ dinv,
                               float* __restrict__ rdinv, int* __restrict__ csr,
                               const float* __restrict__ x, unsigned short* __restrict__ gA) {
    __shared__ int cnt[512];
    __shared__ int excl[512];
    __shared__ int s_deg[512];
    const int j = blockIdx.x, t = threadIdx.x;
    const int ebeg = hist[j * SBLK];
    const int eend = (j == NBK - 1) ? NE : hist[(j + 1) * SBLK];
    cnt[t] = 0;
    __syncthreads();
    for (int e = ebeg + t; e < eend; e += 512)
        atomicAdd(&cnt[buck[e] & 511], 1);
    __syncthreads();
    s_deg[t] = cnt[t];
    excl[t] = cnt[t];
    __syncthreads();
    for (int off = 1; off < 512; off <<= 1) {
        int v = (t >= off) ? excl[t - off] : 0;
        __syncthreads();
        if (t >= off) excl[t] += v;
        __syncthreads();
    }
    const int my_excl = (t == 0) ? 0 : excl[t - 1];
    const int node = j * 512 + t;
    if (node < NN) {
        rowptr[node] = ebeg + my_excl;
        float sq = (float)(s_deg[t] + 1);
        float dv = rsqrtf(sq);
        dinv[node]  = dv;
        rdinv[node] = sq * dv;     // sqrt(deg+1)
    }
    if (j == NBK - 1 && t == 0) rowptr[NN] = NE;
    __syncthreads();
    cnt[t] = ebeg + my_excl;     // cursor
    __syncthreads();
    for (int e = ebeg + t; e < eend; e += 512) {
        unsigned int v = buck[e];
        int pos = atomicAdd(&cnt[v & 511], 1);
        csr[pos] = (int)(v >> 9);
    }
    // fused g0: gA[node][:] = bf16(dinv*x[node][:]); wave-coalesced
    const int wv = t >> 6, ln = t & 63;
    for (int n = wv; n < 512; n += 8) {
        int nd = j * 512 + n;
        if (nd < NN) {
            float dvv = rsqrtf((float)(s_deg[n] + 1));
            gA[nd * HID + ln] = f2bf(dvv * x[nd * HID + ln]);
        }
    }
}

// ---------------- propagation ----------------
// g = dinv*h (bf16). h_next = dv*(sum g[s] + g[v]); gout = dv*h_next.
// STEP2: out = ALPHA*x + COEF*(rdinv*(g1+g2) + h3); routb = bf16(relu(out)).
// One wave/node. grp=lane>>3 (8 edge slots), fl=lane&7 (8 bf16 = 16B per lane).
template <int STEP>
__global__ void prop_kernel(const unsigned short* __restrict__ gin,
                            unsigned short* __restrict__ gout,
                            const unsigned short* __restrict__ g1,
                            const unsigned short* __restrict__ g2,
                            const float* __restrict__ x,
                            const float* __restrict__ dinv,
                            const float* __restrict__ rdinv,
                            const int* __restrict__ rowptr, const int* __restrict__ csr,
                            unsigned short* __restrict__ routb) {
    const int wid = (blockIdx.x * blockDim.x + threadIdx.x) >> 6;
    if (wid >= NN) return;
    const int lane = threadIdx.x & 63;
    const int grp = lane >> 3;
    const int fl  = lane & 7;
    const int beg = rowptr[wid], endp = rowptr[wid + 1];
    float acc[8];
#pragma unroll
    for (int i = 0; i < 8; ++i) acc[i] = 0.f;
    int e = beg + grp;
    for (; e + 8 < endp; e += 16) {       // 16 gathers in flight per wave
        int s0 = csr[e], s1 = csr[e + 8];
        uint4 q0 = *reinterpret_cast<const uint4*>(&gin[s0 * HID + fl * 8]);
        uint4 q1 = *reinterpret_cast<const uint4*>(&gin[s1 * HID + fl * 8]);
        acc2(acc[0], acc[1], q0.x); acc2(acc[2], acc[3], q0.y);
        acc2(acc[4], acc[5], q0.z); acc2(acc[6], acc[7], q0.w);
        acc2(acc[0], acc[1], q1.x); acc2(acc[2], acc[3], q1.y);
        acc2(acc[4], acc[5], q1.z); acc2(acc[6], acc[7], q1.w);
    }
    if (e < endp) {
        int s0 = csr[e];
        uint4 q0 = *reinterpret_cast<const uint4*>(&gin[s0 * HID + fl * 8]);
        acc2(acc[0], acc[1], q0.x); acc2(acc[2], acc[3], q0.y);
        acc2(acc[4], acc[5], q0.z); acc2(acc[6], acc[7], q0.w);
    }
#pragma unroll
    for (int i = 0; i < 8; ++i) {
        acc[i] += __shfl_xor(acc[i], 8, 64);
        acc[i] += __shfl_xor(acc[i], 16, 64);
        acc[i] += __shfl_xor(acc[i], 32, 64);
    }
    if (grp != 0) return;
    const float dv = dinv[wid];
    const int o = wid * HID + fl * 8;
    uint4 qs = *reinterpret_cast<const uint4*>(&gin[o]);
    float s[8];
    up2(s[0], s[1], qs.x); up2(s[2], s[3], qs.y);
    up2(s[4], s[5], qs.z); up2(s[6], s[7], qs.w);
    float h[8];
#pragma unroll
    for (int i = 0; i < 8; ++i) h[i] = dv * (acc[i] + s[i]);
    if (STEP < 2) {
        uint4 gq;
        gq.x = pk2(dv * h[0], dv * h[1]); gq.y = pk2(dv * h[2], dv * h[3]);
        gq.z = pk2(dv * h[4], dv * h[5]); gq.w = pk2(dv * h[6], dv * h[7]);
        *reinterpret_cast<uint4*>(&gout[o]) = gq;
    } else {
        const float rd = rdinv[wid];               // sqrt(deg+1) = 1/dv
        uint4 a1 = *reinterpret_cast<const uint4*>(&g1[o]);
        uint4 a2 = *reinterpret_cast<const uint4*>(&g2[o]);
        float p[8], q[8];
        up2(p[0], p[1], a1.x); up2(p[2], p[3], a1.y);
        up2(p[4], p[5], a1.z); up2(p[6], p[7], a1.w);
        up2(q[0], q[1], a2.x); up2(q[2], q[3], a2.y);
        up2(q[4], q[5], a2.z); up2(q[6], q[7], a2.w);
        float4 x0 = *reinterpret_cast<const float4*>(&x[o]);
        float4 x1 = *reinterpret_cast<const float4*>(&x[o + 4]);
        float xr[8] = {x0.x, x0.y, x0.z, x0.w, x1.x, x1.y, x1.z, x1.w};
        float ov[8];
#pragma unroll
        for (int i = 0; i < 8; ++i)
            ov[i] = fmaxf(ALPHA * xr[i] + COEF * (rd * (p[i] + q[i]) + h[i]), 0.f);
        uint4 r;
        r.x = pk2(ov[0], ov[1]); r.y = pk2(ov[2], ov[3]);
        r.z = pk2(ov[4], ov[5]); r.w = pk2(ov[6], ov[7]);
        *reinterpret_cast<uint4*>(&routb[o]) = r;
    }
}

// ---------------- SimpleConv(mean) of relu(out) + residual + relu ----------------
__global__ void final_kernel(const unsigned short* __restrict__ routb,
                             const float* __restrict__ x,
                             const int* __restrict__ rowptr, const int* __restrict__ csr,
                             float* __restrict__ res) {
    const int wid = (blockIdx.x * blockDim.x + threadIdx.x) >> 6;
    if (wid >= NN) return;
    const int lane = threadIdx.x & 63;
    const int grp = lane >> 3;
    const int fl  = lane & 7;
    const int beg = rowptr[wid], endp = rowptr[wid + 1];
    float acc[8];
#pragma unroll
    for (int i = 0; i < 8; ++i) acc[i] = 0.f;
    int e = beg + grp;
    for (; e + 8 < endp; e += 16) {
        int s0 = csr[e], s1 = csr[e + 8];
        uint4 q0 = *reinterpret_cast<const uint4*>(&routb[s0 * HID + fl * 8]);
        uint4 q1 = *reinterpret_cast<const uint4*>(&routb[s1 * HID + fl * 8]);
        acc2(acc[0], acc[1], q0.x); acc2(acc[2], acc[3], q0.y);
        acc2(acc[4], acc[5], q0.z); acc2(acc[6], acc[7], q0.w);
        acc2(acc[0], acc[1], q1.x); acc2(acc[2], acc[3], q1.y);
        acc2(acc[4], acc[5], q1.z); acc2(acc[6], acc[7], q1.w);
    }
    if (e < endp) {
        int s0 = csr[e];
        uint4 q0 = *reinterpret_cast<const uint4*>(&routb[s0 * HID + fl * 8]);
        acc2(acc[0], acc[1], q0.x); acc2(acc[2], acc[3], q0.y);
        acc2(acc[4], acc[5], q0.z); acc2(acc[6], acc[7], q0.w);
    }
#pragma unroll
    for (int i = 0; i < 8; ++i) {
        acc[i] += __shfl_xor(acc[i], 8, 64);
        acc[i] += __shfl_xor(acc[i], 16, 64);
        acc[i] += __shfl_xor(acc[i], 32, 64);
    }
    if (grp != 0) return;
    const float inv = 1.f / fmaxf((float)(endp - beg), 1.f);
    const int o = wid * HID + fl * 8;
    float4 x0 = *reinterpret_cast<const float4*>(&x[o]);
    float4 x1 = *reinterpret_cast<const float4*>(&x[o + 4]);
    float4 r0, r1;
    r0.x = fmaxf(acc[0] * inv + x0.x, 0.f); r0.y = fmaxf(acc[1] * inv + x0.y, 0.f);
    r0.z = fmaxf(acc[2] * inv + x0.z, 0.f); r0.w = fmaxf(acc[3] * inv + x0.w, 0.f);
    r1.x = fmaxf(acc[4] * inv + x1.x, 0.f); r1.y = fmaxf(acc[5] * inv + x1.y, 0.f);
    r1.z = fmaxf(acc[6] * inv + x1.z, 0.f); r1.w = fmaxf(acc[7] * inv + x1.w, 0.f);
    *reinterpret_cast<float4*>(&res[o])     = r0;
    *reinterpret_cast<float4*>(&res[o + 4]) = r1;
}

extern "C" void kernel_launch(void* const* d_in, const int* in_sizes, int n_in,
                              void* d_out, int out_size, void* d_ws, size_t ws_size,
                              hipStream_t stream) {
    const float* x  = (const float*)d_in[0];
    const int* ei   = (const int*)d_in[1];      // (2, NE): [src | dst]
    const int* srcp = ei;
    const int* dstp = ei + NE;
    float* resp     = (float*)d_out;

    size_t off = 0;
    auto carve = [&](size_t bytes) { size_t p = off; off = (off + bytes + 255) & ~(size_t)255; return p; };
    char* ws = (char*)d_ws;
    int*          hist   = (int*)          (ws + carve((size_t)HTOT * 4));
    int*          hsum   = (int*)          (ws + carve((size_t)64 * 4));
    unsigned int* buck   = (unsigned int*) (ws + carve((size_t)NE * 4));
    int*          rowptr = (int*)          (ws + carve((size_t)(NN + 1) * 4));
    float*        dinv   = (float*)        (ws + carve((size_t)NN * 4));
    float*        rdinv  = (float*)        (ws + carve((size_t)NN * 4));
    int*          csr    = (int*)          (ws + carve((size_t)NE * 4));
    unsigned short* gA    = (unsigned short*)(ws + carve((size_t)NN * HID * 2));
    unsigned short* gB    = (unsigned short*)(ws + carve((size_t)NN * HID * 2));
    unsigned short* gC    = (unsigned short*)(ws + carve((size_t)NN * HID * 2));
    unsigned short* routb = (unsigned short*)(ws + carve((size_t)NN * HID * 2));
    (void)ws_size; (void)n_in; (void)in_sizes; (void)out_size;

    histA_kernel<<<SBLK, 256, 0, stream>>>(dstp, hist);
    scanHA_kernel<<<HTOT / 1024, 1024, 0, stream>>>(hist, hsum);
    scanHC_kernel<<<HTOT / 1024, 1024, 0, stream>>>(hist, hsum);
    scatterB_kernel<<<SBLK, 256, 0, stream>>>(srcp, dstp, hist, buck);
    bucketC_kernel<<<NBK, 512, 0, stream>>>(buck, hist, rowptr, dinv, rdinv, csr, x, gA);

    const int nblk = 256;                            // 4 nodes/block (1 wave each)
    const int ngrid = (NN + 3) / 4;                  // 25000
    prop_kernel<0><<<ngrid, nblk, 0, stream>>>(gA, gB, nullptr, nullptr, nullptr, dinv, rdinv, rowptr, csr, nullptr);
    prop_kernel<1><<<ngrid, nblk, 0, stream>>>(gB, gC, nullptr, nullptr, nullptr, dinv, rdinv, rowptr, csr, nullptr);
    prop_kernel<2><<<ngrid, nblk, 0, stream>>>(gC, nullptr, gB, gC, x, dinv, rdinv, rowptr, csr, routb);
    final_kernel<<<ngrid, nblk, 0, stream>>>(routb, x, rowptr, csr, resp);
}

// Round 7
// 306.408 us; speedup vs baseline: 1.0829x; 1.0829x over previous
//
#include <hip/hip_runtime.h>
#include <hip/hip_bf16.h>

#define NN 100000
#define NE 1600000
#define HID 64
#define ALPHA 0.1f
#define COEF 0.3f   // (1-ALPHA)/K

#define NBK 392            // buckets of 256 nodes: dst>>8 (bucket 391 empty)
#define SBLK 256           // blocks for hist/scatter passes
#define EB_PER_BLK (NE / SBLK)   // 6250
#define HTOT (NBK * SBLK)        // 100352 = 98 * 1024
#define EVC 12             // per-thread register edge cache in bucketC

__device__ __forceinline__ float bf2f(unsigned short u) {
    union { unsigned int i; float f; } v; v.i = ((unsigned int)u) << 16; return v.f;
}
__device__ __forceinline__ unsigned short f2bf(float f) {
    union { float f; unsigned int i; } v; v.f = f;
    unsigned int r = v.i + 0x7FFF + ((v.i >> 16) & 1);
    return (unsigned short)(r >> 16);
}
// lo gets exact bf16; hi keeps low-16-bit mantissa contamination (<=1 ulp bf16) — saves the AND
__device__ __forceinline__ void acc2(float& lo, float& hi, unsigned int u) {
    union { unsigned int i; float f; } a, b;
    a.i = u << 16; b.i = u;
    lo += a.f; hi += b.f;
}
__device__ __forceinline__ void up2(float& lo, float& hi, unsigned int u) {
    union { unsigned int i; float f; } a, b;
    a.i = u << 16; b.i = u & 0xFFFF0000u;
    lo = a.f; hi = b.f;
}
__device__ __forceinline__ unsigned int pk2(float lo, float hi) {
    return (unsigned int)f2bf(lo) | ((unsigned int)f2bf(hi) << 16);
}

// ---------------- bucketed CSR build (no global atomics) ----------------

__global__ void histA_kernel(const int* __restrict__ dst, int* __restrict__ hist) {
    __shared__ int cnt[NBK];
    const int b = blockIdx.x, t = threadIdx.x;
    for (int i = t; i < NBK; i += 256) cnt[i] = 0;
    __syncthreads();
    const int beg = b * EB_PER_BLK, end = beg + EB_PER_BLK;
    for (int e = beg + t; e < end; e += 256)
        atomicAdd(&cnt[dst[e] >> 8], 1);
    __syncthreads();
    for (int i = t; i < NBK; i += 256)
        hist[i * SBLK + b] = cnt[i];
}

// coalesced 2-kernel scan of hist[HTOT]
__global__ void scanHA_kernel(const int* __restrict__ hist, int* __restrict__ hsum) {
    __shared__ int red[16];
    const int b = blockIdx.x, t = threadIdx.x;
    int v = hist[b * 1024 + t];
    for (int o = 32; o > 0; o >>= 1) v += __shfl_down(v, o, 64);
    if ((t & 63) == 0) red[t >> 6] = v;
    __syncthreads();
    if (t < 64) {
        int s = (t < 16) ? red[t] : 0;
        for (int o = 8; o > 0; o >>= 1) s += __shfl_down(s, o, 64);
        if (t == 0) hsum[b] = s;
    }
}

__global__ void scanHC_kernel(int* __restrict__ hist, const int* __restrict__ hsum) {
    __shared__ int ts[1024];
    __shared__ int s_off;
    const int b = blockIdx.x, t = threadIdx.x;
    int v = hist[b * 1024 + t];
    ts[t] = v;
    if (t == 0) {
        int o = 0;
        for (int i = 0; i < b; ++i) o += hsum[i];
        s_off = o;
    }
    __syncthreads();
    for (int off = 1; off < 1024; off <<= 1) {
        int w = (t >= off) ? ts[t - off] : 0;
        __syncthreads();
        if (t >= off) ts[t] += w;
        __syncthreads();
    }
    hist[b * 1024 + t] = s_off + ((t > 0) ? ts[t - 1] : 0);
}

__global__ void scatterB_kernel(const int* __restrict__ src, const int* __restrict__ dst,
                                const int* __restrict__ hist, unsigned int* __restrict__ buck) {
    __shared__ int cur[NBK];
    const int b = blockIdx.x, t = threadIdx.x;
    for (int i = t; i < NBK; i += 256) cur[i] = hist[i * SBLK + b];
    __syncthreads();
    const int beg = b * EB_PER_BLK, end = beg + EB_PER_BLK;
    for (int e = beg + t; e < end; e += 256) {
        int d = dst[e];
        int pos = atomicAdd(&cur[d >> 8], 1);
        buck[pos] = ((unsigned int)src[e] << 8) | (unsigned int)(d & 255);
    }
}

// Per-bucket (256 nodes, 512 thr): rowptr/dinv/rdinv + csr scatter from reg-cached edges.
__global__ void bucketC_kernel(const unsigned int* __restrict__ buck, const int* __restrict__ hist,
                               int* __restrict__ rowptr, float* __restrict__ dinv,
                               float* __restrict__ rdinv, int* __restrict__ csr) {
    __shared__ int cnt[256];
    __shared__ int excl[256];
    __shared__ int curs[256];
    const int j = blockIdx.x, t = threadIdx.x;
    const int ebeg = hist[j * SBLK];
    const int eend = (j == NBK - 1) ? NE : hist[(j + 1) * SBLK];
    if (t < 256) cnt[t] = 0;
    __syncthreads();
    unsigned int ev[EVC];
    int m = 0;
    for (int e = ebeg + t; e < eend; e += 512) {
        unsigned int v = buck[e];
        atomicAdd(&cnt[v & 255], 1);
        if (m < EVC) ev[m++] = v;
    }
    __syncthreads();
    if (t < 256) excl[t] = cnt[t];
    __syncthreads();
    for (int off = 1; off < 256; off <<= 1) {
        int v = (t >= off && t < 256) ? excl[t - off] : 0;
        __syncthreads();
        if (t >= off && t < 256) excl[t] += v;
        __syncthreads();
    }
    if (t < 256) {
        const int my_excl = excl[t] - cnt[t];
        const int node = j * 256 + t;
        if (node < NN) {
            rowptr[node] = ebeg + my_excl;
            float sq = (float)(cnt[t] + 1);
            float dv = rsqrtf(sq);
            dinv[node]  = dv;
            rdinv[node] = sq * dv;     // sqrt(deg+1)
        }
        curs[t] = ebeg + my_excl;
    }
    if (j == NBK - 1 && t == 0) rowptr[NN] = NE;
    __syncthreads();
    for (int i = 0; i < m; ++i) {
        unsigned int v = ev[i];
        int pos = atomicAdd(&curs[v & 255], 1);
        csr[pos] = (int)(v >> 8);
    }
    // overflow fallback (rare): edges beyond the register cache
    for (int e = ebeg + t + EVC * 512; e < eend; e += 512) {
        unsigned int v = buck[e];
        int pos = atomicAdd(&curs[v & 255], 1);
        csr[pos] = (int)(v >> 8);
    }
}

// g0 = bf16(dinv[v] * x[v])
__global__ void g0_kernel(const float* __restrict__ x, const float* __restrict__ dinv,
                          unsigned short* __restrict__ g0) {
    int i = blockIdx.x * blockDim.x + threadIdx.x;
    if (i >= NN * HID / 4) return;
    float dv = dinv[(i * 4) >> 6];
    float4 v = *reinterpret_cast<const float4*>(&x[i * 4]);
    ushort4 u;
    u.x = f2bf(dv * v.x); u.y = f2bf(dv * v.y);
    u.z = f2bf(dv * v.z); u.w = f2bf(dv * v.w);
    *reinterpret_cast<ushort4*>(&g0[i * 4]) = u;
}

// ---------------- propagation ----------------
// g = dinv*h (bf16). h_next = dv*(sum g[s] + g[v]); gout = dv*h_next.
// STEP2: out = ALPHA*x + COEF*(rdinv*(g1+g2) + h3); routb = bf16(relu(out)).
// One wave/node. grp=lane>>3 (8 edge slots), fl=lane&7 (8 bf16 = 16B per lane).
template <int STEP>
__global__ void prop_kernel(const unsigned short* __restrict__ gin,
                            unsigned short* __restrict__ gout,
                            const unsigned short* __restrict__ g1,
                            const unsigned short* __restrict__ g2,
                            const float* __restrict__ x,
                            const float* __restrict__ dinv,
                            const float* __restrict__ rdinv,
                            const int* __restrict__ rowptr, const int* __restrict__ csr,
                            unsigned short* __restrict__ routb) {
    const int wid = (blockIdx.x * blockDim.x + threadIdx.x) >> 6;
    if (wid >= NN) return;
    const int lane = threadIdx.x & 63;
    const int grp = lane >> 3;
    const int fl  = lane & 7;
    const int beg = rowptr[wid], endp = rowptr[wid + 1];
    float acc[8];
#pragma unroll
    for (int i = 0; i < 8; ++i) acc[i] = 0.f;
    int e = beg + grp;
    for (; e + 8 < endp; e += 16) {       // 16 gathers in flight per wave
        int s0 = csr[e], s1 = csr[e + 8];
        uint4 q0 = *reinterpret_cast<const uint4*>(&gin[s0 * HID + fl * 8]);
        uint4 q1 = *reinterpret_cast<const uint4*>(&gin[s1 * HID + fl * 8]);
        acc2(acc[0], acc[1], q0.x); acc2(acc[2], acc[3], q0.y);
        acc2(acc[4], acc[5], q0.z); acc2(acc[6], acc[7], q0.w);
        acc2(acc[0], acc[1], q1.x); acc2(acc[2], acc[3], q1.y);
        acc2(acc[4], acc[5], q1.z); acc2(acc[6], acc[7], q1.w);
    }
    if (e < endp) {
        int s0 = csr[e];
        uint4 q0 = *reinterpret_cast<const uint4*>(&gin[s0 * HID + fl * 8]);
        acc2(acc[0], acc[1], q0.x); acc2(acc[2], acc[3], q0.y);
        acc2(acc[4], acc[5], q0.z); acc2(acc[6], acc[7], q0.w);
    }
#pragma unroll
    for (int i = 0; i < 8; ++i) {
        acc[i] += __shfl_xor(acc[i], 8, 64);
        acc[i] += __shfl_xor(acc[i], 16, 64);
        acc[i] += __shfl_xor(acc[i], 32, 64);
    }
    if (grp != 0) return;
    const float dv = dinv[wid];
    const int o = wid * HID + fl * 8;
    uint4 qs = *reinterpret_cast<const uint4*>(&gin[o]);
    float s[8];
    up2(s[0], s[1], qs.x); up2(s[2], s[3], qs.y);
    up2(s[4], s[5], qs.z); up2(s[6], s[7], qs.w);
    float h[8];
#pragma unroll
    for (int i = 0; i < 8; ++i) h[i] = dv * (acc[i] + s[i]);
    if (STEP < 2) {
        uint4 gq;
        gq.x = pk2(dv * h[0], dv * h[1]); gq.y = pk2(dv * h[2], dv * h[3]);
        gq.z = pk2(dv * h[4], dv * h[5]); gq.w = pk2(dv * h[6], dv * h[7]);
        *reinterpret_cast<uint4*>(&gout[o]) = gq;
    } else {
        const float rd = rdinv[wid];               // sqrt(deg+1) = 1/dv
        uint4 a1 = *reinterpret_cast<const uint4*>(&g1[o]);
        uint4 a2 = *reinterpret_cast<const uint4*>(&g2[o]);
        float p[8], q[8];
        up2(p[0], p[1], a1.x); up2(p[2], p[3], a1.y);
        up2(p[4], p[5], a1.z); up2(p[6], p[7], a1.w);
        up2(q[0], q[1], a2.x); up2(q[2], q[3], a2.y);
        up2(q[4], q[5], a2.z); up2(q[6], q[7], a2.w);
        float4 x0 = *reinterpret_cast<const float4*>(&x[o]);
        float4 x1 = *reinterpret_cast<const float4*>(&x[o + 4]);
        float xr[8] = {x0.x, x0.y, x0.z, x0.w, x1.x, x1.y, x1.z, x1.w};
        float ov[8];
#pragma unroll
        for (int i = 0; i < 8; ++i)
            ov[i] = fmaxf(ALPHA * xr[i] + COEF * (rd * (p[i] + q[i]) + h[i]), 0.f);
        uint4 r;
        r.x = pk2(ov[0], ov[1]); r.y = pk2(ov[2], ov[3]);
        r.z = pk2(ov[4], ov[5]); r.w = pk2(ov[6], ov[7]);
        *reinterpret_cast<uint4*>(&routb[o]) = r;
    }
}

// ---------------- SimpleConv(mean) of relu(out) + residual + relu ----------------
__global__ void final_kernel(const unsigned short* __restrict__ routb,
                             const float* __restrict__ x,
                             const int* __restrict__ rowptr, const int* __restrict__ csr,
                             float* __restrict__ res) {
    const int wid = (blockIdx.x * blockDim.x + threadIdx.x) >> 6;
    if (wid >= NN) return;
    const int lane = threadIdx.x & 63;
    const int grp = lane >> 3;
    const int fl  = lane & 7;
    const int beg = rowptr[wid], endp = rowptr[wid + 1];
    float acc[8];
#pragma unroll
    for (int i = 0; i < 8; ++i) acc[i] = 0.f;
    int e = beg + grp;
    for (; e + 8 < endp; e += 16) {
        int s0 = csr[e], s1 = csr[e + 8];
        uint4 q0 = *reinterpret_cast<const uint4*>(&routb[s0 * HID + fl * 8]);
        uint4 q1 = *reinterpret_cast<const uint4*>(&routb[s1 * HID + fl * 8]);
        acc2(acc[0], acc[1], q0.x); acc2(acc[2], acc[3], q0.y);
        acc2(acc[4], acc[5], q0.z); acc2(acc[6], acc[7], q0.w);
        acc2(acc[0], acc[1], q1.x); acc2(acc[2], acc[3], q1.y);
        acc2(acc[4], acc[5], q1.z); acc2(acc[6], acc[7], q1.w);
    }
    if (e < endp) {
        int s0 = csr[e];
        uint4 q0 = *reinterpret_cast<const uint4*>(&routb[s0 * HID + fl * 8]);
        acc2(acc[0], acc[1], q0.x); acc2(acc[2], acc[3], q0.y);
        acc2(acc[4], acc[5], q0.z); acc2(acc[6], acc[7], q0.w);
    }
#pragma unroll
    for (int i = 0; i < 8; ++i) {
        acc[i] += __shfl_xor(acc[i], 8, 64);
        acc[i] += __shfl_xor(acc[i], 16, 64);
        acc[i] += __shfl_xor(acc[i], 32, 64);
    }
    if (grp != 0) return;
    const float inv = 1.f / fmaxf((float)(endp - beg), 1.f);
    const int o = wid * HID + fl * 8;
    float4 x0 = *reinterpret_cast<const float4*>(&x[o]);
    float4 x1 = *reinterpret_cast<const float4*>(&x[o + 4]);
    float4 r0, r1;
    r0.x = fmaxf(acc[0] * inv + x0.x, 0.f); r0.y = fmaxf(acc[1] * inv + x0.y, 0.f);
    r0.z = fmaxf(acc[2] * inv + x0.z, 0.f); r0.w = fmaxf(acc[3] * inv + x0.w, 0.f);
    r1.x = fmaxf(acc[4] * inv + x1.x, 0.f); r1.y = fmaxf(acc[5] * inv + x1.y, 0.f);
    r1.z = fmaxf(acc[6] * inv + x1.z, 0.f); r1.w = fmaxf(acc[7] * inv + x1.w, 0.f);
    *reinterpret_cast<float4*>(&res[o])     = r0;
    *reinterpret_cast<float4*>(&res[o + 4]) = r1;
}

extern "C" void kernel_launch(void* const* d_in, const int* in_sizes, int n_in,
                              void* d_out, int out_size, void* d_ws, size_t ws_size,
                              hipStream_t stream) {
    const float* x  = (const float*)d_in[0];
    const int* ei   = (const int*)d_in[1];      // (2, NE): [src | dst]
    const int* srcp = ei;
    const int* dstp = ei + NE;
    float* resp     = (float*)d_out;

    size_t off = 0;
    auto carve = [&](size_t bytes) { size_t p = off; off = (off + bytes + 255) & ~(size_t)255; return p; };
    char* ws = (char*)d_ws;
    int*          hist   = (int*)          (ws + carve((size_t)HTOT * 4));
    int*          hsum   = (int*)          (ws + carve((size_t)128 * 4));
    unsigned int* buck   = (unsigned int*) (ws + carve((size_t)NE * 4));
    int*          rowptr = (int*)          (ws + carve((size_t)(NN + 1) * 4));
    float*        dinv   = (float*)        (ws + carve((size_t)NN * 4));
    float*        rdinv  = (float*)        (ws + carve((size_t)NN * 4));
    int*          csr    = (int*)          (ws + carve((size_t)NE * 4));
    unsigned short* gA    = (unsigned short*)(ws + carve((size_t)NN * HID * 2));
    unsigned short* gB    = (unsigned short*)(ws + carve((size_t)NN * HID * 2));
    unsigned short* gC    = (unsigned short*)(ws + carve((size_t)NN * HID * 2));
    unsigned short* routb = (unsigned short*)(ws + carve((size_t)NN * HID * 2));
    (void)ws_size; (void)n_in; (void)in_sizes; (void)out_size;

    histA_kernel<<<SBLK, 256, 0, stream>>>(dstp, hist);
    scanHA_kernel<<<HTOT / 1024, 1024, 0, stream>>>(hist, hsum);
    scanHC_kernel<<<HTOT / 1024, 1024, 0, stream>>>(hist, hsum);
    scatterB_kernel<<<SBLK, 256, 0, stream>>>(srcp, dstp, hist, buck);
    bucketC_kernel<<<NBK, 512, 0, stream>>>(buck, hist, rowptr, dinv, rdinv, csr);
    g0_kernel<<<(NN * HID / 4 + 255) / 256, 256, 0, stream>>>(x, dinv, gA);

    const int nblk = 256;                            // 4 nodes/block (1 wave each)
    const int ngrid = (NN + 3) / 4;                  // 25000
    prop_kernel<0><<<ngrid, nblk, 0, stream>>>(gA, gB, nullptr, nullptr, nullptr, dinv, rdinv, rowptr, csr, nullptr);
    prop_kernel<1><<<ngrid, nblk, 0, stream>>>(gB, gC, nullptr, nullptr, nullptr, dinv, rdinv, rowptr, csr, nullptr);
    prop_kernel<2><<<ngrid, nblk, 0, stream>>>(gC, nullptr, gB, gC, x, dinv, rdinv, rowptr, csr, routb);
    final_kernel<<<ngrid, nblk, 0, stream>>>(routb, x, rowptr, csr, resp);
}

// Round 9
// 291.816 us; speedup vs baseline: 1.1370x; 1.0500x over previous
//
#include <hip/hip_runtime.h>
#include <hip/hip_bf16.h>

#define NN 100000
#define NE 1600000
#define HID 64
#define ALPHA 0.1f
#define COEF 0.3f   // (1-ALPHA)/K

#define NBK 392            // buckets of 256 nodes: dst>>8
#define SBLK 256           // blocks for hist/scatter passes (SBLK*NBK <= NE/16 keeps runs >= 1 line)
#define EB_PER_BLK (NE / SBLK)   // 6250
#define HTOT (NBK * SBLK)        // 100352 = 98 * 1024
#define EVC 12             // per-thread register edge cache in bucketC

// hardware packed f32->bf16 (RNE), 1 VALU op for 2 values [T12, m214v22 verified on gfx950]
__device__ __forceinline__ unsigned int cvtpk(float lo, float hi) {
    unsigned int r;
    asm("v_cvt_pk_bf16_f32 %0, %1, %2" : "=v"(r) : "v"(lo), "v"(hi));
    return r;
}
__device__ __forceinline__ unsigned short f2bf(float f) {
    union { float f; unsigned int i; } v; v.f = f;
    unsigned int r = v.i + 0x7FFF + ((v.i >> 16) & 1);
    return (unsigned short)(r >> 16);
}
// lo exact bf16; hi keeps low-16-bit mantissa contamination (<=1 ulp bf16) — saves the AND
__device__ __forceinline__ void acc2(float& lo, float& hi, unsigned int u) {
    union { unsigned int i; float f; } a, b;
    a.i = u << 16; b.i = u;
    lo += a.f; hi += b.f;
}
__device__ __forceinline__ void up2(float& lo, float& hi, unsigned int u) {
    union { unsigned int i; float f; } a, b;
    a.i = u << 16; b.i = u;
    lo = a.f; hi = b.f;
}

// ---------------- bucketed CSR build (no global atomics) ----------------

__global__ void histA_kernel(const int* __restrict__ dst, int* __restrict__ hist) {
    __shared__ int cnt[NBK];
    const int b = blockIdx.x, t = threadIdx.x;
    for (int i = t; i < NBK; i += 256) cnt[i] = 0;
    __syncthreads();
    const int beg = b * EB_PER_BLK, end = beg + EB_PER_BLK;
    for (int e = beg + t; e < end; e += 256)
        atomicAdd(&cnt[dst[e] >> 8], 1);
    __syncthreads();
    for (int i = t; i < NBK; i += 256)
        hist[i * SBLK + b] = cnt[i];
}

// coalesced 2-kernel scan of hist[HTOT]
__global__ void scanHA_kernel(const int* __restrict__ hist, int* __restrict__ hsum) {
    __shared__ int red[16];
    const int b = blockIdx.x, t = threadIdx.x;
    int v = hist[b * 1024 + t];
    for (int o = 32; o > 0; o >>= 1) v += __shfl_down(v, o, 64);
    if ((t & 63) == 0) red[t >> 6] = v;
    __syncthreads();
    if (t < 64) {
        int s = (t < 16) ? red[t] : 0;
        for (int o = 8; o > 0; o >>= 1) s += __shfl_down(s, o, 64);
        if (t == 0) hsum[b] = s;
    }
}

__global__ void scanHC_kernel(int* __restrict__ hist, const int* __restrict__ hsum) {
    __shared__ int ts[1024];
    __shared__ int s_off;
    const int b = blockIdx.x, t = threadIdx.x;
    int v = hist[b * 1024 + t];
    ts[t] = v;
    if (t == 0) {
        int o = 0;
        for (int i = 0; i < b; ++i) o += hsum[i];
        s_off = o;
    }
    __syncthreads();
    for (int off = 1; off < 1024; off <<= 1) {
        int w = (t >= off) ? ts[t - off] : 0;
        __syncthreads();
        if (t >= off) ts[t] += w;
        __syncthreads();
    }
    hist[b * 1024 + t] = s_off + ((t > 0) ? ts[t - 1] : 0);
}

__global__ void scatterB_kernel(const int* __restrict__ src, const int* __restrict__ dst,
                                const int* __restrict__ hist, unsigned int* __restrict__ buck) {
    __shared__ int cur[NBK];
    const int b = blockIdx.x, t = threadIdx.x;
    for (int i = t; i < NBK; i += 256) cur[i] = hist[i * SBLK + b];
    __syncthreads();
    const int beg = b * EB_PER_BLK, end = beg + EB_PER_BLK;
    for (int e = beg + t; e < end; e += 256) {
        int d = dst[e];
        int pos = atomicAdd(&cur[d >> 8], 1);
        buck[pos] = ((unsigned int)src[e] << 8) | (unsigned int)(d & 255);
    }
}

// Per-bucket (256 nodes, 512 thr): rowptr/dinv/rdinv + csr scatter from reg-cached edges.
// csr stores src*HID (pre-scaled element offset).
__global__ void bucketC_kernel(const unsigned int* __restrict__ buck, const int* __restrict__ hist,
                               int* __restrict__ rowptr, float* __restrict__ dinv,
                               float* __restrict__ rdinv, int* __restrict__ csr) {
    __shared__ int cnt[256];
    __shared__ int excl[256];
    __shared__ int curs[256];
    const int j = blockIdx.x, t = threadIdx.x;
    const int ebeg = hist[j * SBLK];
    const int eend = (j == NBK - 1) ? NE : hist[(j + 1) * SBLK];
    if (t < 256) cnt[t] = 0;
    __syncthreads();
    unsigned int ev[EVC];
    int m = 0;
    for (int e = ebeg + t; e < eend; e += 512) {
        unsigned int v = buck[e];
        atomicAdd(&cnt[v & 255], 1);
        if (m < EVC) ev[m++] = v;
    }
    __syncthreads();
    if (t < 256) excl[t] = cnt[t];
    __syncthreads();
    for (int off = 1; off < 256; off <<= 1) {
        int v = (t >= off && t < 256) ? excl[t - off] : 0;
        __syncthreads();
        if (t >= off && t < 256) excl[t] += v;
        __syncthreads();
    }
    if (t < 256) {
        const int my_excl = excl[t] - cnt[t];
        const int node = j * 256 + t;
        if (node < NN) {
            rowptr[node] = ebeg + my_excl;
            float sq = (float)(cnt[t] + 1);
            float dv = rsqrtf(sq);
            dinv[node]  = dv;
            rdinv[node] = sq * dv;     // sqrt(deg+1)
        }
        curs[t] = ebeg + my_excl;
    }
    if (j == NBK - 1 && t == 0) rowptr[NN] = NE;
    __syncthreads();
    for (int i = 0; i < m; ++i) {
        unsigned int v = ev[i];
        int pos = atomicAdd(&curs[v & 255], 1);
        csr[pos] = (int)((v >> 8) << 6);          // src*HID
    }
    for (int e = ebeg + t + EVC * 512; e < eend; e += 512) {
        unsigned int v = buck[e];
        int pos = atomicAdd(&curs[v & 255], 1);
        csr[pos] = (int)((v >> 8) << 6);
    }
}

// g0 = bf16(dinv[v] * x[v])
__global__ void g0_kernel(const float* __restrict__ x, const float* __restrict__ dinv,
                          unsigned short* __restrict__ g0) {
    int i = blockIdx.x * blockDim.x + threadIdx.x;
    if (i >= NN * HID / 4) return;
    float dv = dinv[(i * 4) >> 6];
    float4 v = *reinterpret_cast<const float4*>(&x[i * 4]);
    uint2 u;
    u.x = cvtpk(dv * v.x, dv * v.y);
    u.y = cvtpk(dv * v.z, dv * v.w);
    *reinterpret_cast<uint2*>(&g0[i * 4]) = u;
}

// ---------------- propagation ----------------
// g = dinv*h (bf16). STEP<2: gout = dv^2*(acc+s). STEP2: out = ALPHA*x + COEF*(rdinv*(g1+g2)+h3),
// routb = bf16(relu(out)). One wave/node; grp=lane>>3 (8 edge slots), fl=lane&7 (8 bf16/lane).
template <int STEP>
__global__ void prop_kernel(const unsigned short* __restrict__ gin,
                            unsigned short* __restrict__ gout,
                            const unsigned short* __restrict__ g1,
                            const unsigned short* __restrict__ g2,
                            const float* __restrict__ x,
                            const float* __restrict__ dinv,
                            const float* __restrict__ rdinv,
                            const int* __restrict__ rowptr, const int* __restrict__ csr,
                            unsigned short* __restrict__ routb) {
    const int wid = (blockIdx.x * blockDim.x + threadIdx.x) >> 6;
    if (wid >= NN) return;
    const int lane = threadIdx.x & 63;
    const int grp = lane >> 3;
    const int fl8 = (lane & 7) * 8;
    const int beg = rowptr[wid], endp = rowptr[wid + 1];
    const float dv = dinv[wid];
    const int o = wid * HID + fl8;
    uint4 qs = *reinterpret_cast<const uint4*>(&gin[o]);   // self row, hoisted
    float acc[8];
#pragma unroll
    for (int i = 0; i < 8; ++i) acc[i] = 0.f;
    int e = beg + grp;
    for (; e + 8 < endp; e += 16) {       // 16 gathers in flight per wave
        int s0 = csr[e], s1 = csr[e + 8];            // pre-scaled src*HID
        uint4 q0 = *reinterpret_cast<const uint4*>(&gin[s0 + fl8]);
        uint4 q1 = *reinterpret_cast<const uint4*>(&gin[s1 + fl8]);
        acc2(acc[0], acc[1], q0.x); acc2(acc[2], acc[3], q0.y);
        acc2(acc[4], acc[5], q0.z); acc2(acc[6], acc[7], q0.w);
        acc2(acc[0], acc[1], q1.x); acc2(acc[2], acc[3], q1.y);
        acc2(acc[4], acc[5], q1.z); acc2(acc[6], acc[7], q1.w);
    }
    if (e < endp) {
        int s0 = csr[e];
        uint4 q0 = *reinterpret_cast<const uint4*>(&gin[s0 + fl8]);
        acc2(acc[0], acc[1], q0.x); acc2(acc[2], acc[3], q0.y);
        acc2(acc[4], acc[5], q0.z); acc2(acc[6], acc[7], q0.w);
    }
#pragma unroll
    for (int i = 0; i < 8; ++i) {
        acc[i] += __shfl_xor(acc[i], 8, 64);
        acc[i] += __shfl_xor(acc[i], 16, 64);
        acc[i] += __shfl_xor(acc[i], 32, 64);
    }
    if (grp != 0) return;
    float s[8];
    up2(s[0], s[1], qs.x); up2(s[2], s[3], qs.y);
    up2(s[4], s[5], qs.z); up2(s[6], s[7], qs.w);
    if (STEP < 2) {
        const float dv2 = dv * dv;
        uint4 gq;
        gq.x = cvtpk(dv2 * (acc[0] + s[0]), dv2 * (acc[1] + s[1]));
        gq.y = cvtpk(dv2 * (acc[2] + s[2]), dv2 * (acc[3] + s[3]));
        gq.z = cvtpk(dv2 * (acc[4] + s[4]), dv2 * (acc[5] + s[5]));
        gq.w = cvtpk(dv2 * (acc[6] + s[6]), dv2 * (acc[7] + s[7]));
        *reinterpret_cast<uint4*>(&gout[o]) = gq;
    } else {
        const float rd = rdinv[wid];               // sqrt(deg+1) = 1/dv
        uint4 a1 = *reinterpret_cast<const uint4*>(&g1[o]);
        uint4 a2 = *reinterpret_cast<const uint4*>(&g2[o]);
        float p[8], q[8];
        up2(p[0], p[1], a1.x); up2(p[2], p[3], a1.y);
        up2(p[4], p[5], a1.z); up2(p[6], p[7], a1.w);
        up2(q[0], q[1], a2.x); up2(q[2], q[3], a2.y);
        up2(q[4], q[5], a2.z); up2(q[6], q[7], a2.w);
        float4 x0 = *reinterpret_cast<const float4*>(&x[o]);
        float4 x1 = *reinterpret_cast<const float4*>(&x[o + 4]);
        float xr[8] = {x0.x, x0.y, x0.z, x0.w, x1.x, x1.y, x1.z, x1.w};
        float ov[8];
#pragma unroll
        for (int i = 0; i < 8; ++i) {
            float h = dv * (acc[i] + s[i]);
            ov[i] = fmaxf(fmaf(ALPHA, xr[i], COEF * fmaf(rd, p[i] + q[i], h)), 0.f);
        }
        uint4 r;
        r.x = cvtpk(ov[0], ov[1]); r.y = cvtpk(ov[2], ov[3]);
        r.z = cvtpk(ov[4], ov[5]); r.w = cvtpk(ov[6], ov[7]);
        *reinterpret_cast<uint4*>(&routb[o]) = r;
    }
}

// ---------------- SimpleConv(mean) of relu(out) + residual + relu ----------------
__global__ void final_kernel(const unsigned short* __restrict__ routb,
                             const float* __restrict__ x,
                             const int* __restrict__ rowptr, const int* __restrict__ csr,
                             float* __restrict__ res) {
    const int wid = (blockIdx.x * blockDim.x + threadIdx.x) >> 6;
    if (wid >= NN) return;
    const int lane = threadIdx.x & 63;
    const int grp = lane >> 3;
    const int fl8 = (lane & 7) * 8;
    const int beg = rowptr[wid], endp = rowptr[wid + 1];
    float acc[8];
#pragma unroll
    for (int i = 0; i < 8; ++i) acc[i] = 0.f;
    int e = beg + grp;
    for (; e + 8 < endp; e += 16) {
        int s0 = csr[e], s1 = csr[e + 8];
        uint4 q0 = *reinterpret_cast<const uint4*>(&routb[s0 + fl8]);
        uint4 q1 = *reinterpret_cast<const uint4*>(&routb[s1 + fl8]);
        acc2(acc[0], acc[1], q0.x); acc2(acc[2], acc[3], q0.y);
        acc2(acc[4], acc[5], q0.z); acc2(acc[6], acc[7], q0.w);
        acc2(acc[0], acc[1], q1.x); acc2(acc[2], acc[3], q1.y);
        acc2(acc[4], acc[5], q1.z); acc2(acc[6], acc[7], q1.w);
    }
    if (e < endp) {
        int s0 = csr[e];
        uint4 q0 = *reinterpret_cast<const uint4*>(&routb[s0 + fl8]);
        acc2(acc[0], acc[1], q0.x); acc2(acc[2], acc[3], q0.y);
        acc2(acc[4], acc[5], q0.z); acc2(acc[6], acc[7], q0.w);
    }
#pragma unroll
    for (int i = 0; i < 8; ++i) {
        acc[i] += __shfl_xor(acc[i], 8, 64);
        acc[i] += __shfl_xor(acc[i], 16, 64);
        acc[i] += __shfl_xor(acc[i], 32, 64);
    }
    if (grp != 0) return;
    const float inv = 1.f / fmaxf((float)(endp - beg), 1.f);
    const int o = wid * HID + fl8;
    float4 x0 = *reinterpret_cast<const float4*>(&x[o]);
    float4 x1 = *reinterpret_cast<const float4*>(&x[o + 4]);
    float4 r0, r1;
    r0.x = fmaxf(fmaf(acc[0], inv, x0.x), 0.f); r0.y = fmaxf(fmaf(acc[1], inv, x0.y), 0.f);
    r0.z = fmaxf(fmaf(acc[2], inv, x0.z), 0.f); r0.w = fmaxf(fmaf(acc[3], inv, x0.w), 0.f);
    r1.x = fmaxf(fmaf(acc[4], inv, x1.x), 0.f); r1.y = fmaxf(fmaf(acc[5], inv, x1.y), 0.f);
    r1.z = fmaxf(fmaf(acc[6], inv, x1.z), 0.f); r1.w = fmaxf(fmaf(acc[7], inv, x1.w), 0.f);
    *reinterpret_cast<float4*>(&res[o])     = r0;
    *reinterpret_cast<float4*>(&res[o + 4]) = r1;
}

extern "C" void kernel_launch(void* const* d_in, const int* in_sizes, int n_in,
                              void* d_out, int out_size, void* d_ws, size_t ws_size,
                              hipStream_t stream) {
    const float* x  = (const float*)d_in[0];
    const int* ei   = (const int*)d_in[1];      // (2, NE): [src | dst]
    const int* srcp = ei;
    const int* dstp = ei + NE;
    float* resp     = (float*)d_out;

    size_t off = 0;
    auto carve = [&](size_t bytes) { size_t p = off; off = (off + bytes + 255) & ~(size_t)255; return p; };
    char* ws = (char*)d_ws;
    int*          hist   = (int*)          (ws + carve((size_t)HTOT * 4));
    int*          hsum   = (int*)          (ws + carve((size_t)128 * 4));
    unsigned int* buck   = (unsigned int*) (ws + carve((size_t)NE * 4));
    int*          rowptr = (int*)          (ws + carve((size_t)(NN + 1) * 4));
    float*        dinv   = (float*)        (ws + carve((size_t)NN * 4));
    float*        rdinv  = (float*)        (ws + carve((size_t)NN * 4));
    int*          csr    = (int*)          (ws + carve((size_t)NE * 4));
    unsigned short* gA    = (unsigned short*)(ws + carve((size_t)NN * HID * 2));
    unsigned short* gB    = (unsigned short*)(ws + carve((size_t)NN * HID * 2));
    unsigned short* gC    = (unsigned short*)(ws + carve((size_t)NN * HID * 2));
    unsigned short* routb = (unsigned short*)(ws + carve((size_t)NN * HID * 2));
    (void)ws_size; (void)n_in; (void)in_sizes; (void)out_size;

    histA_kernel<<<SBLK, 256, 0, stream>>>(dstp, hist);
    scanHA_kernel<<<HTOT / 1024, 1024, 0, stream>>>(hist, hsum);
    scanHC_kernel<<<HTOT / 1024, 1024, 0, stream>>>(hist, hsum);
    scatterB_kernel<<<SBLK, 256, 0, stream>>>(srcp, dstp, hist, buck);
    bucketC_kernel<<<NBK, 512, 0, stream>>>(buck, hist, rowptr, dinv, rdinv, csr);
    g0_kernel<<<(NN * HID / 4 + 255) / 256, 256, 0, stream>>>(x, dinv, gA);

    const int nblk = 256;                            // 4 nodes/block (1 wave each)
    const int ngrid = (NN + 3) / 4;                  // 25000
    prop_kernel<0><<<ngrid, nblk, 0, stream>>>(gA, gB, nullptr, nullptr, nullptr, dinv, rdinv, rowptr, csr, nullptr);
    prop_kernel<1><<<ngrid, nblk, 0, stream>>>(gB, gC, nullptr, nullptr, nullptr, dinv, rdinv, rowptr, csr, nullptr);
    prop_kernel<2><<<ngrid, nblk, 0, stream>>>(gC, nullptr, gB, gC, x, dinv, rdinv, rowptr, csr, routb);
    final_kernel<<<ngrid, nblk, 0, stream>>>(routb, x, rowptr, csr, resp);
}